// Round 7
// baseline (230.883 us; speedup 1.0000x reference)
//
#include <hip/hip_runtime.h>
#include <math.h>

#define NORB 13
#define NORB2 (NORB * NORB)
#define NTHR 256
#define MAXE 256               // entries incident to one atom (mean ~32)
#define NBIN 128               // partner-atom bins (N <= 128)
#define MAXB 129               // distinct nonzero blocks (<= NBIN + diag)

typedef float fx2 __attribute__((ext_vector_type(2)));
typedef float fx4 __attribute__((ext_vector_type(4)));

// block id per orbital index for L_LIST=[0,0,1,1,2] -> sizes 1,1,3,3,5
__device__ __forceinline__ int blk_of(int p) {
    return p < 1 ? 0 : (p < 2 ? 1 : (p < 5 ? 2 : (p < 8 ? 3 : 4)));
}
__device__ __forceinline__ float bfac(int bp, int bq) {
    return bp < bq ? 1.0f : (bp == bq ? 0.5f : 0.0f);
}

// ---- phase 1: fill-clone zero kernel (pure streaming dwordx4 stores) ------
__global__ void __launch_bounds__(NTHR)
k_zero(float* __restrict__ out, size_t nfx4) {
    size_t i = (size_t)blockIdx.x * NTHR + threadIdx.x;
    size_t stride = (size_t)gridDim.x * NTHR;
    fx4* o = (fx4*)out;
    fx4 z = (fx4){0.f, 0.f, 0.f, 0.f};
    for (; i < nfx4; i += stride) o[i] = z;
}

// ---- phase 2: sparse block writer -----------------------------------------
// One WG per (k, a): CSR-bin the ~32 incident entries by partner atom b,
// precompute phases, then compute each DISTINCT nonzero 13x13 block once and
// scatter it (~27 blocks x 1352 B = ~37 KB per WG, ~75 MB total).
__global__ void __launch_bounds__(NTHR)
k_sparse(const float* __restrict__ hopping,
         const float* __restrict__ onsite,
         const float* __restrict__ kpoints,
         const float* __restrict__ cell_shift,
         const int* __restrict__ edge_index,
         float* __restrict__ out,
         int N, int E, int K, int ld, int es) {
    int a = blockIdx.x % N;
    int k = blockIdx.x / N;
    int tid = threadIdx.x;

    __shared__ int   boff[NBIN + 1];   // counts -> CSR offsets
    __shared__ int   cur[NBIN];        // placement cursors
    __shared__ int   elist[MAXE];      // (e<<8) | (b<<1) | rev, sorted by b
    __shared__ float phc[MAXE];        // cos
    __shared__ float phs[MAXE];        // sin (sign-folded: conj for rev)
    __shared__ int   nzb[MAXB];        // b | i0<<7 | i1<<16
    __shared__ int   nnz;

    if (tid < NBIN) boff[tid] = 0;
    if (tid == 0) nnz = 0;
    __syncthreads();

    // count entries per partner atom b (edge list is 16 KB, L2-hot)
    for (int e = tid; e < E; e += NTHR) {
        int ie = edge_index[e], je = edge_index[E + e];
        if (ie == a) atomicAdd(&boff[je], 1);
        if (je == a) atomicAdd(&boff[ie], 1);
    }
    __syncthreads();

    // exclusive prefix over 128 bins: wave 0, 2 bins/lane, shfl scan
    if (tid < 64) {
        int v0 = boff[2 * tid], v1 = boff[2 * tid + 1];
        int s = v0 + v1, sc = s;
        #pragma unroll
        for (int d = 1; d < 64; d <<= 1) {
            int t = __shfl_up(sc, d);
            if (tid >= d) sc += t;
        }
        int excl = sc - s;
        boff[2 * tid] = excl;          cur[2 * tid] = excl;
        boff[2 * tid + 1] = excl + v0; cur[2 * tid + 1] = excl + v0;
        if (tid == 63) boff[NBIN] = sc;
    }
    __syncthreads();

    // place entries (counting sort by b)
    for (int e = tid; e < E; e += NTHR) {
        int ie = edge_index[e], je = edge_index[E + e];
        if (ie == a) {
            int pos = atomicAdd(&cur[je], 1);
            if (pos < MAXE) elist[pos] = (e << 8) | (je << 1);        // fwd
        }
        if (je == a) {
            int pos = atomicAdd(&cur[ie], 1);
            if (pos < MAXE) elist[pos] = (e << 8) | (ie << 1) | 1;    // rev
        }
    }
    __syncthreads();
    int nent = min(boff[NBIN], MAXE);

    // phases for this WG's single k
    float kx = kpoints[3 * k], ky = kpoints[3 * k + 1], kz = kpoints[3 * k + 2];
    for (int t = tid; t < nent; t += NTHR) {
        int ent = elist[t];
        int e = ent >> 8;
        float d = kx * cell_shift[3 * e] + ky * cell_shift[3 * e + 1]
                + kz * cell_shift[3 * e + 2];
        float s, c;
        __sincosf(-6.2831853071795864f * d, &s, &c);   // exp(-i*2pi*d) = c + i*s
        phc[t] = c;
        phs[t] = (ent & 1) ? -s : s;                   // conj for reverse
    }

    // enumerate nonzero blocks (bins with entries, plus the onsite diagonal)
    if (tid < NBIN) {
        int i0 = boff[tid];
        int i1 = boff[tid + 1]; if (i1 > MAXE) i1 = MAXE;
        if (i1 > i0 || tid == a) {
            int s = atomicAdd(&nnz, 1);
            nzb[s] = tid | (i0 << 7) | (i1 << 16);
        }
    }
    __syncthreads();
    int nb = nnz;

    const float* on = onsite + (size_t)a * NORB2;
    size_t rb = (size_t)(k * ld + a * NORB) * ld;      // complex units

    int tot = nb * NORB2;
    for (int idx = tid; idx < tot; idx += NTHR) {
        int blk = idx / NORB2;             // const-169 magic div
        int r   = idx - blk * NORB2;
        int p = r / NORB, q = r - p * NORB; // const-13 magic div
        int info = nzb[blk];
        int b  = info & 127;
        int i0 = (info >> 7) & 511, i1 = (info >> 16) & 511;
        int bp = blk_of(p), bq = blk_of(q);
        float fpq = bfac(bp, bq), fqp = bfac(bq, bp);
        float ax = 0.f, ay = 0.f;
        if (b == a)                         // hermitized onsite (real)
            ax = on[p * NORB + q] * fpq + on[q * NORB + p] * fqp;
        for (int it = i0; it < i1; ++it) {
            int ent = elist[it];
            const float* h = hopping + (size_t)(ent >> 8) * NORB2;
            float hv = (ent & 1) ? h[q * NORB + p] * fqp
                                 : h[p * NORB + q] * fpq;
            ax += phc[it] * hv;
            ay += phs[it] * hv;
        }
        size_t ci = rb + (size_t)p * ld + (size_t)b * NORB + q;
        if (es == 2) ((fx2*)out)[ci] = (fx2){ax, ay};
        else         out[ci] = ax;
    }
}

extern "C" void kernel_launch(void* const* d_in, const int* in_sizes, int n_in,
                              void* d_out, int out_size, void* d_ws, size_t ws_size,
                              hipStream_t stream) {
    const float* hopping    = (const float*)d_in[0];
    const float* onsite     = (const float*)d_in[1];
    const float* kpoints    = (const float*)d_in[2];
    const float* cell_shift = (const float*)d_in[3];
    const int*   edge_index = (const int*)d_in[4];
    float* out = (float*)d_out;

    int E = in_sizes[0] / NORB2;   // 2048
    int N = in_sizes[1] / NORB2;   // 128
    int K = in_sizes[2] / 3;       // 16
    int ld = N * NORB;             // 1664

    size_t full = (size_t)K * ld * ld * 2;             // floats if complex
    int es = ((size_t)out_size >= full) ? 2 : 1;
    size_t nfloats = (size_t)K * ld * ld * (es == 2 ? 2 : 1);

    // phase 1: zero the full output (pure streaming; fill-clone)
    k_zero<<<8192, NTHR, 0, stream>>>(out, nfloats / 4);

    // phase 2: scatter nonzero 13x13 blocks (stream-ordered after zeros)
    int nwg = N * K;               // 2048 WGs
    k_sparse<<<nwg, NTHR, 0, stream>>>(hopping, onsite, kpoints, cell_shift,
                                       edge_index, out, N, E, K, ld, es);
}

// Round 8
// 214.552 us; speedup vs baseline: 1.0761x; 1.0761x over previous
//
#include <hip/hip_runtime.h>
#include <math.h>

#define NORB 13
#define NORB2 (NORB * NORB)
#define GB 16                  // b-atoms per group; strip row = 208 complex = 1664 B
#define NCOL (GB * NORB)       // 208 columns per strip
#define KSPLIT 2               // k-chunks per bin
#define MAXE 128               // per-bin entry capacity (mean ~4)
#define NTHR 256

typedef float fx2 __attribute__((ext_vector_type(2)));

// block id per orbital index for L_LIST=[0,0,1,1,2] -> sizes 1,1,3,3,5
__device__ __forceinline__ int blk_of(int p) {
    return p < 1 ? 0 : (p < 2 ? 1 : (p < 5 ? 2 : (p < 8 ? 3 : 4)));
}
__device__ __forceinline__ float bfac(int bp, int bq) {
    return bp < bq ? 1.0f : (bp == bq ? 0.5f : 0.0f);
}

// One WG per (a, b-group, k-chunk). Thread = one strip COLUMN c = i*13+q;
// accumulates all 13 rows in registers, stores each row as a wave-dense
// contiguous run. Stores are NONTEMPORAL: stream past L2/L3 so the write
// path drains at DRAM-sequential rate instead of dirty-eviction rate.
__global__ void __launch_bounds__(NTHR)
k_fused(const float* __restrict__ hopping,
        const float* __restrict__ onsite,
        const float* __restrict__ kpoints,
        const float* __restrict__ cell_shift,
        const int* __restrict__ edge_index,
        float* __restrict__ out,
        int N, int E, int K, int ld, int es, int ngroups) {
    int g  = blockIdx.x % ngroups;
    int a  = (blockIdx.x / ngroups) % N;
    int kc = blockIdx.x / (ngroups * N);
    int kch = (K + KSPLIT - 1) / KSPLIT;
    int k0 = kc * kch, k1 = min(K, k0 + kch);
    int tid = threadIdx.x;
    int b0 = g * GB;

    __shared__ int ecnt;
    __shared__ int list[MAXE];   // (e<<5) | (b_slot<<1) | rev

    if (tid == 0) ecnt = 0;
    __syncthreads();

    // scan tiny edge list (16 KB, L1-hot) for entries hitting this (a,g) bin
    for (int e = tid; e < E; e += NTHR) {
        int ie = edge_index[e], je = edge_index[E + e];
        if (ie == a && (je >> 4) == g) {
            int pos = atomicAdd(&ecnt, 1);
            if (pos < MAXE) list[pos] = (e << 5) | ((je & 15) << 1);       // fwd
        }
        if (je == a && (ie >> 4) == g) {
            int pos = atomicAdd(&ecnt, 1);
            if (pos < MAXE) list[pos] = (e << 5) | ((ie & 15) << 1) | 1;   // rev
        }
    }
    __syncthreads();
    int nent = min(__builtin_amdgcn_readfirstlane(ecnt), MAXE);

    // broadcast list into registers: lane l of every wave holds list[l];
    // per-entry access becomes one v_readlane (no LDS latency in k-loop)
    int lane = tid & 63;
    int myent = (lane < nent) ? list[lane] : 0;

    int c = tid;                              // strip column
    if (c >= NCOL || g * NCOL + c >= ld) return;
    int i_c = c / NORB;                       // b-slot of this column
    int q   = c - i_c * NORB;                 // orbital col within block
    int bq  = blk_of(q);
    bool diagact = (b0 + i_c == a);
    const float* on = onsite + (size_t)a * NORB2;

    for (int k = k0; k < k1; ++k) {
        float kx = kpoints[3 * k], ky = kpoints[3 * k + 1], kz = kpoints[3 * k + 2];

        // init accumulators with hermitized onsite (diagonal block only, real)
        float ax[NORB], ay[NORB];
        #pragma unroll
        for (int p = 0; p < NORB; ++p) {
            float v = 0.f;
            if (diagact) {
                int bp = blk_of(p);           // compile-time per unrolled p
                v = on[p * NORB + q] * bfac(bp, bq)
                  + on[q * NORB + p] * bfac(bq, bp);
            }
            ax[p] = v; ay[p] = 0.f;
        }

        for (int it = 0; it < nent; ++it) {
            int ent = (it < 64) ? __builtin_amdgcn_readlane(myent, it) : list[it];
            int e = ent >> 5;
            int islot = (ent >> 1) & 15;
            int rev = ent & 1;
            const float* cs = cell_shift + 3 * (size_t)e;
            float d = kx * cs[0] + ky * cs[1] + kz * cs[2];
            float s, cc;
            __sincosf(-6.2831853071795864f * d, &s, &cc);   // exp(-i*2pi*d)=cc+i*s
            float sv = rev ? -s : s;                        // conj for reverse
            if (i_c == islot) {                             // 13 lanes active
                const float* h = hopping + (size_t)e * NORB2;
                if (rev) {
                    #pragma unroll
                    for (int p = 0; p < NORB; ++p) {
                        float hv = h[q * NORB + p] * bfac(bq, blk_of(p));
                        ax[p] += cc * hv; ay[p] += sv * hv;
                    }
                } else {
                    #pragma unroll
                    for (int p = 0; p < NORB; ++p) {
                        float hv = h[p * NORB + q] * bfac(blk_of(p), bq);
                        ax[p] += cc * hv; ay[p] += sv * hv;
                    }
                }
            }
        }

        // store: per p, lanes 0..207 write 1664 contiguous bytes (64B-aligned),
        // nontemporal (stream to DRAM, don't allocate dirty L2/L3 lines)
        size_t base = ((size_t)(k * ld + a * NORB)) * ld + (size_t)g * NCOL + c;
        if (es == 2) {
            fx2* o2 = (fx2*)out;
            #pragma unroll
            for (int p = 0; p < NORB; ++p) {
                fx2 v = (fx2){ax[p], ay[p]};
                __builtin_nontemporal_store(v, &o2[base + (size_t)p * ld]);
            }
        } else {
            #pragma unroll
            for (int p = 0; p < NORB; ++p)
                __builtin_nontemporal_store(ax[p], &out[base + (size_t)p * ld]);
        }
    }
}

extern "C" void kernel_launch(void* const* d_in, const int* in_sizes, int n_in,
                              void* d_out, int out_size, void* d_ws, size_t ws_size,
                              hipStream_t stream) {
    const float* hopping    = (const float*)d_in[0];
    const float* onsite     = (const float*)d_in[1];
    const float* kpoints    = (const float*)d_in[2];
    const float* cell_shift = (const float*)d_in[3];
    const int*   edge_index = (const int*)d_in[4];
    float* out = (float*)d_out;

    int E = in_sizes[0] / NORB2;   // 2048
    int N = in_sizes[1] / NORB2;   // 128
    int K = in_sizes[2] / 3;       // 16
    int ld = N * NORB;             // 1664
    int ngroups = (N + GB - 1) / GB;   // 8

    size_t full = (size_t)K * ld * ld * 2;
    int es = ((size_t)out_size >= full) ? 2 : 1;

    int nwg = N * ngroups * KSPLIT;    // 2048 WGs
    k_fused<<<nwg, NTHR, 0, stream>>>(hopping, onsite, kpoints, cell_shift,
                                      edge_index, out, N, E, K, ld, es, ngroups);
}